// Round 16
// baseline (390.731 us; speedup 1.0000x reference)
//
#include <hip/hip_runtime.h>

typedef unsigned short ushort_t;
typedef unsigned int uint_t;

typedef __attribute__((ext_vector_type(8))) short bf16x8;
typedef __attribute__((ext_vector_type(4))) float f32x4;
typedef __attribute__((ext_vector_type(2))) float f32x2;

#define GLOAD16(g, l) __builtin_amdgcn_global_load_lds( \
    (const __attribute__((address_space(1))) unsigned int*)(g), \
    (__attribute__((address_space(3))) unsigned int*)(l), 16, 0, 0)

#define VMCNT4 asm volatile("s_waitcnt vmcnt(4)" ::: "memory")
#define VMCNT2 asm volatile("s_waitcnt vmcnt(2)" ::: "memory")
#define VMCNT0 asm volatile("s_waitcnt vmcnt(0)" ::: "memory")
#define LGKM0  asm volatile("s_waitcnt lgkmcnt(0)" ::: "memory")
#define BARX   __builtin_amdgcn_s_barrier()

__device__ __forceinline__ ushort_t f2bf(float f) {
  union { float f; uint_t u; } c; c.f = f;
  uint_t u = c.u;
  return (ushort_t)((u + 0x7FFFu + ((u >> 16) & 1u)) >> 16);
}

// monotone order-preserving bf16 -> u16 key (bijective)
__device__ __forceinline__ ushort_t bf2key(ushort_t u) {
  return (u & 0x8000u) ? (ushort_t)(~u) : (ushort_t)(u | 0x8000u);
}

// ---------------- prep: x -> bf16, colsum, sumsq ----------------
__global__ __launch_bounds__(256) void prep_x(const float* __restrict__ x,
                                              ushort_t* __restrict__ xbf,
                                              float* __restrict__ colsum,
                                              double* __restrict__ accs) {
  const int tid = threadIdx.x;
  const int r0 = blockIdx.x * 32;
  float cs0 = 0.f, cs1 = 0.f, cs2 = 0.f;
  double ss = 0.0;
  for (int r = 0; r < 32; ++r) {
    const float* xr = x + (size_t)(r0 + r) * 768;
    ushort_t* xo = xbf + (size_t)(r0 + r) * 768;
    float v0 = xr[tid], v1 = xr[tid + 256], v2 = xr[tid + 512];
    xo[tid] = f2bf(v0); xo[tid + 256] = f2bf(v1); xo[tid + 512] = f2bf(v2);
    cs0 += v0; cs1 += v1; cs2 += v2;
    ss += (double)v0 * v0 + (double)v1 * v1 + (double)v2 * v2;
  }
  atomicAdd(&colsum[tid], cs0);
  atomicAdd(&colsum[tid + 256], cs1);
  atomicAdd(&colsum[tid + 512], cs2);
  for (int o = 32; o > 0; o >>= 1) ss += __shfl_down(ss, o);
  __shared__ double wsum[4];
  if ((tid & 63) == 0) wsum[tid >> 6] = ss;
  __syncthreads();
  if (tid == 0) atomicAdd(&accs[5], wsum[0] + wsum[1] + wsum[2] + wsum[3]);
}

// ---------------- generic f32 -> bf16 convert ----------------
__global__ __launch_bounds__(256) void conv_bf16(const float* __restrict__ in,
                                                 ushort_t* __restrict__ out, int n) {
  int i = (blockIdx.x * 256 + threadIdx.x) * 4;
  if (i + 3 < n) {
    float4 v = *(const float4*)(in + i);
    uint_t a = (uint_t)f2bf(v.x) | ((uint_t)f2bf(v.y) << 16);
    uint_t b = (uint_t)f2bf(v.z) | ((uint_t)f2bf(v.w) << 16);
    *(uint2*)(out + i) = make_uint2(a, b);
  }
}

// ---------------- W_dec f32 -> fp8 e4m3 (x16 scale), 4 cols per uint ----------------
__global__ __launch_bounds__(256) void conv_fp8(const float* __restrict__ in,
                                                uint_t* __restrict__ out, int n4) {
  int i = blockIdx.x * 256 + threadIdx.x;
  if (i < n4) {
    float4 v = ((const float4*)in)[i];
    int w = 0;
    w = __builtin_amdgcn_cvt_pk_fp8_f32(v.x * 16.f, v.y * 16.f, w, false);
    w = __builtin_amdgcn_cvt_pk_fp8_f32(v.z * 16.f, v.w * 16.f, w, true);
    out[i] = (uint_t)w;
  }
}

// ---------------- W_skip transpose -> bf16 [D][K], LDS-tiled ----------------
__global__ __launch_bounds__(256) void conv_skipT(const float* __restrict__ in,
                                                  ushort_t* __restrict__ out) {
  __shared__ ushort_t tile[64][65];
  const int bx = blockIdx.x % 12, by = blockIdx.x / 12;
  const int lx = threadIdx.x & 63, ly = threadIdx.x >> 6;
#pragma unroll
  for (int r = 0; r < 16; ++r) {
    const int k = by * 64 + ly * 16 + r;
    tile[ly * 16 + r][lx] = f2bf(in[(size_t)k * 768 + bx * 64 + lx]);
  }
  __syncthreads();
#pragma unroll
  for (int r = 0; r < 16; ++r) {
    const int d = bx * 64 + ly * 16 + r;
    out[(size_t)d * 768 + by * 64 + lx] = tile[lx][ly * 16 + r];
  }
}

// ---------------- small bf16 GEMM (skip path): m97 structure ----------------
__global__ __launch_bounds__(256) void gemm_bt(const ushort_t* __restrict__ Ag,
                                               const ushort_t* __restrict__ Bg,
                                               float* __restrict__ Cg,
                                               const float* __restrict__ bias,
                                               int K, int ldc) {
  __shared__ __align__(16) char smem[34816];
  const int tid = threadIdx.x;
  const int lane = tid & 63, wid = tid >> 6;
  const int wr = wid >> 1, wc = wid & 1;
  const int lo = lane & 15, hi = lane >> 4;
  const int arow0 = blockIdx.y * 128, brow0 = blockIdx.x * 128;
  const int rr0 = (lane >> 2);
  const int kb = (lane & 3) * 8;
  f32x4 acc[4][4] = {};
  const int NT = K >> 5;
  for (int c = 0; c < 2; ++c) {
    int rr = (wid * 2 + c) * 16 + rr0;
    GLOAD16(Ag + (size_t)(arow0 + rr) * K + kb, smem + (wid * 2 + c) * 1024);
    GLOAD16(Bg + (size_t)(brow0 + rr) * K + kb, smem + 16384 + (wid * 2 + c) * 1024);
  }
  __syncthreads();
  for (int kt = 0; kt < NT; ++kt) {
    const int cur = (kt & 1) * 8192;
    const int nxt = 8192 - cur;
    if (kt + 1 < NT) {
      const int k0 = (kt + 1) << 5;
      for (int c = 0; c < 2; ++c) {
        int rr = (wid * 2 + c) * 16 + rr0;
        GLOAD16(Ag + (size_t)(arow0 + rr) * K + k0 + kb, smem + nxt + (wid * 2 + c) * 1024);
        GLOAD16(Bg + (size_t)(brow0 + rr) * K + k0 + kb, smem + 16384 + nxt + (wid * 2 + c) * 1024);
      }
    }
    const char* As = smem + cur;
    const char* Bs = smem + 16384 + cur;
    bf16x8 af[4], bfr[4];
#pragma unroll
    for (int m = 0; m < 4; ++m)
      af[m] = *(const bf16x8*)(As + ((wr * 64 + m * 16 + lo) * 64 + hi * 16));
#pragma unroll
    for (int n = 0; n < 4; ++n)
      bfr[n] = *(const bf16x8*)(Bs + ((wc * 64 + n * 16 + lo) * 64 + hi * 16));
#pragma unroll
    for (int m = 0; m < 4; ++m)
#pragma unroll
      for (int n = 0; n < 4; ++n)
        acc[m][n] = __builtin_amdgcn_mfma_f32_16x16x32_bf16(af[m], bfr[n], acc[m][n], 0, 0, 0);
    __syncthreads();
  }
#pragma unroll
  for (int n = 0; n < 4; ++n) {
    const int col = wc * 64 + n * 16 + lo;
    const float bv = bias[brow0 + col];
#pragma unroll
    for (int m = 0; m < 4; ++m)
#pragma unroll
      for (int r = 0; r < 4; ++r) {
        const int row = wr * 64 + m * 16 + hi * 4 + r;
        Cg[(size_t)(arow0 + row) * (size_t)ldc + brow0 + col] = acc[m][n][r] + bv;
      }
  }
}

// ---------------- 256x256 phase-pipelined bf16 GEMM; writes monotone u16 KEYS ----------------
#define STAGE(G, grow0, kcol, L, S0, SS) do { \
    const int r_ = tid >> 3; \
    const int row_ = (S0) + (r_ & 31) + ((r_ >> 5) * (SS)); \
    GLOAD16((G) + (size_t)((grow0) + row_) * K + (kcol) + ((((tid & 7) ^ (r_ & 7))) << 3), \
            (L) + row_ * 128 + ((tid & 7) << 4)); \
  } while (0)

#define RD_A(MH) do { \
    _Pragma("unroll") for (int m_ = 0; m_ < 4; ++m_) { \
      const int row_ = wr * 128 + (MH) * 64 + m_ * 16 + lo; \
      _Pragma("unroll") for (int ks_ = 0; ks_ < 2; ++ks_) \
        af[m_][ks_] = *(const bf16x8*)(As + row_ * 128 + (((ks_ * 4 + hi) ^ (lo & 7)) << 4)); \
    } } while (0)

#define RD_B(NH, DST) do { \
    _Pragma("unroll") for (int n_ = 0; n_ < 2; ++n_) { \
      const int row_ = wc * 64 + (NH) * 32 + n_ * 16 + lo; \
      _Pragma("unroll") for (int ks_ = 0; ks_ < 2; ++ks_) \
        DST[n_][ks_] = *(const bf16x8*)(Bs + row_ * 128 + (((ks_ * 4 + hi) ^ (lo & 7)) << 4)); \
    } } while (0)

#define MM(MB, NB, BF) do { \
    __builtin_amdgcn_s_setprio(1); \
    _Pragma("unroll") for (int m_ = 0; m_ < 4; ++m_) \
      _Pragma("unroll") for (int n_ = 0; n_ < 2; ++n_) { \
        acc[(MB) + m_][(NB) + n_] = __builtin_amdgcn_mfma_f32_16x16x32_bf16(af[m_][0], BF[n_][0], acc[(MB) + m_][(NB) + n_], 0, 0, 0); \
        acc[(MB) + m_][(NB) + n_] = __builtin_amdgcn_mfma_f32_16x16x32_bf16(af[m_][1], BF[n_][1], acc[(MB) + m_][(NB) + n_], 0, 0, 0); \
      } \
    __builtin_amdgcn_s_setprio(0); \
  } while (0)

__global__ __launch_bounds__(512) void gemm256(const ushort_t* __restrict__ Ag,
                                               const ushort_t* __restrict__ Bg,
                                               ushort_t* __restrict__ Cg,
                                               const float* __restrict__ bias,
                                               int K, int ldc) {
  __shared__ __align__(16) char smem[69632];
  char* As = smem;
  char* Bs = smem + 32768;
  const int tid = threadIdx.x;
  const int lane = tid & 63, wid = tid >> 6;
  const int wr = wid >> 2, wc = wid & 3;
  const int lo = lane & 15, hi = lane >> 4;

  // L2-aware 2D mapping: each XCD owns 8 rows x 24 cols, as three 8x8 super-tiles.
  const int xcd = blockIdx.x & 7;
  const int idx = blockIdx.x >> 3;
  const int rg = xcd >> 1;
  const int cg = xcd & 1;
  const int st = idx >> 6;
  const int wi = idx & 63;
  const int brow0 = (rg * 8 + (wi & 7)) * 256;
  const int bcol0 = (cg * 24 + st * 8 + (wi >> 3)) * 256;

  const int NT = K >> 6;
  f32x4 acc[8][4] = {};
  bf16x8 af[4][2], b0[2][2], b1[2][2];

  STAGE(Ag, brow0, 0, As, 0, 32);   STAGE(Ag, brow0, 0, As, 128, 32);
  STAGE(Bg, bcol0, 0, Bs, 0, 64);   STAGE(Bg, bcol0, 0, Bs, 128, 64);
  STAGE(Bg, bcol0, 0, Bs, 32, 64);  STAGE(Bg, bcol0, 0, Bs, 160, 64);

  for (int kt = 0; kt < NT - 1; ++kt) {
    const int k0 = kt << 6, k1 = (kt + 1) << 6;
    STAGE(Ag, brow0, k0, As, 64, 32);  STAGE(Ag, brow0, k0, As, 192, 32);
    VMCNT4; BARX;
    RD_A(0); RD_B(0, b0);
    MM(0, 0, b0);
    BARX;
    STAGE(Ag, brow0, k1, As, 0, 32);   STAGE(Ag, brow0, k1, As, 128, 32);
    VMCNT4; BARX;
    RD_B(1, b1);
    MM(0, 2, b1);
    BARX;
    STAGE(Bg, bcol0, k1, Bs, 0, 64);   STAGE(Bg, bcol0, k1, Bs, 128, 64);
    VMCNT4; BARX;
    RD_A(1);
    MM(4, 0, b0);
    BARX;
    STAGE(Bg, bcol0, k1, Bs, 32, 64);  STAGE(Bg, bcol0, k1, Bs, 160, 64);
    MM(4, 2, b1);
  }
  {
    const int k0 = (NT - 1) << 6;
    STAGE(Ag, brow0, k0, As, 64, 32);  STAGE(Ag, brow0, k0, As, 192, 32);
    VMCNT4; BARX;
    RD_A(0); RD_B(0, b0);
    MM(0, 0, b0);
    BARX;
    VMCNT2; BARX;
    RD_B(1, b1);
    MM(0, 2, b1);
    BARX;
    VMCNT0; BARX;
    RD_A(1);
    MM(4, 0, b0);
    MM(4, 2, b1);
  }
  BARX;

  ushort_t* rep = (ushort_t*)smem;
#pragma unroll
  for (int h = 0; h < 2; ++h) {
    if (wr == h) {
#pragma unroll
      for (int n = 0; n < 4; ++n) {
        const int cl = wc * 64 + n * 16 + lo;
        const float bv = bias[bcol0 + cl];
#pragma unroll
        for (int m = 0; m < 8; ++m)
#pragma unroll
          for (int r = 0; r < 4; ++r)
            rep[(m * 16 + hi * 4 + r) * 264 + cl] = bf2key(f2bf(acc[m][n][r] + bv));
      }
    }
    LGKM0; BARX;
    {
      const int rl = tid >> 2;
      const int c0 = tid & 3;
      ushort_t* dst = Cg + (size_t)(brow0 + h * 128 + rl) * (size_t)ldc + bcol0;
#pragma unroll
      for (int p = 0; p < 8; ++p)
        *(uint4*)(dst + (c0 + p * 4) * 8) = *(const uint4*)(rep + rl * 264 + (c0 + p * 4) * 8);
    }
    LGKM0; BARX;
  }
}

// ---------------- fused top-k + sparse decode + loss (pre holds u16 keys) ----------------
#define EIDX(c, h) ((uint_t)(((c) >> 2) * 2048 + tid * 8 + (((c) & 3) << 1) + (h)))
#define HW(b) (((b) >> 4) * 17 + ((b) & 15))
__global__ __launch_bounds__(256) void topk_decode(const ushort_t* __restrict__ pre,
                                                   const float* __restrict__ skip,
                                                   const float* __restrict__ mlp,
                                                   const uint_t* __restrict__ Wd8,
                                                   double* __restrict__ pS1,
                                                   double* __restrict__ pS2,
                                                   double* __restrict__ pL1,
                                                   double* __restrict__ pL2,
                                                   double* __restrict__ pDS) {
  __shared__ uint_t hist[4352];
  __shared__ uint_t cand[256];
  __shared__ uint_t wtot[4];
  __shared__ uint_t ctl[4];
  __shared__ int lidx[128];
  __shared__ float lval[128];   // stores val * 0.0625 (exact pow-2 scale)
  __shared__ double wred[4][3];
  const int tid = threadIdx.x;
  const int lane = tid & 63, wid = tid >> 6;
  const size_t row = blockIdx.x;
  const uint4* pr4 = (const uint4*)(pre + row * 12288);

  float4 s4 = make_float4(0.f, 0.f, 0.f, 0.f), m4 = s4;
  if (tid < 192) {
    s4 = ((const float4*)(skip + row * 768))[tid];
    m4 = ((const float4*)(mlp + row * 768))[tid];
  }

  for (int i = tid; i < 4352; i += 256) hist[i] = 0;
  if (tid < 4) ctl[tid] = 0;
  __syncthreads();

  // pass 1: load row (keys precomputed by gemm256), histogram
  uint_t k2[24];
#pragma unroll
  for (int i = 0; i < 6; ++i) {
    uint4 q = pr4[i * 256 + tid];
    uint_t qq[4] = { q.x, q.y, q.z, q.w };
#pragma unroll
    for (int w = 0; w < 4; ++w) {
      uint_t kk = qq[w];
      k2[i * 4 + w] = kk;
      atomicAdd(&hist[HW((kk & 0xFFFFu) >> 4)], 1u);
      atomicAdd(&hist[HW(kk >> 20)], 1u);
    }
  }
  __syncthreads();

  uint_t cs = 0;
#pragma unroll
  for (int b = 0; b < 16; ++b) cs += hist[tid * 17 + b];
  uint_t s = cs;
#pragma unroll
  for (int off = 1; off < 64; off <<= 1) {
    uint_t v = (uint_t)__shfl_down((int)s, off);
    if (lane + off < 64) s += v;
  }
  if (lane == 0) wtot[wid] = s;
  __syncthreads();
  uint_t above = 0;
  for (int w = wid + 1; w < 4; ++w) above += wtot[w];
  const uint_t Sg = s + above;
  const uint_t Snx = Sg - cs;
  if (Sg >= 128u && Snx < 128u) {
    uint_t running = Snx;
    for (int b = 15; b >= 0; --b) {
      uint_t c = hist[tid * 17 + b];
      if (running + c >= 128u) { ctl[0] = (uint_t)(tid * 16 + b); break; }
      running += c;
    }
  }
  __syncthreads();
  const uint_t b128 = ctl[0];

#pragma unroll
  for (int c = 0; c < 24; ++c) {
    uint_t kk = k2[c];
    uint_t key0 = kk & 0xFFFFu, key1 = kk >> 16;
    if ((key0 >> 4) >= b128) {
      uint_t p = atomicAdd(&ctl[1], 1u);
      if (p < 256u) cand[p] = ((0xFFFFu - key0) << 16) | EIDX(c, 0);
    }
    if ((key1 >> 4) >= b128) {
      uint_t p = atomicAdd(&ctl[1], 1u);
      if (p < 256u) cand[p] = ((0xFFFFu - key1) << 16) | EIDX(c, 1);
    }
  }
  __syncthreads();

  if (wid == 0) {
    const int n = (int)min(ctl[1], 256u);
    uint_t v[4];
#pragma unroll
    for (int r = 0; r < 4; ++r)
      v[r] = (r * 64 + lane < n) ? cand[r * 64 + lane] : 0xFFFFFFFFu;
#pragma unroll
    for (int k = 2; k <= 256; k <<= 1) {
#pragma unroll
      for (int j = 128; j > 0; j >>= 1) {
        if (j >= k) continue;
        if (j >= 64) {
          const int js = j >> 6;
#pragma unroll
          for (int r = 0; r < 4; ++r) {
            if ((r & js) == 0) {
              const int r2 = r | js;
              const bool up = (((r << 6) & k) == 0);
              uint_t a = v[r], b = v[r2];
              uint_t mn = min(a, b), mx = max(a, b);
              v[r] = up ? mn : mx;
              v[r2] = up ? mx : mn;
            }
          }
        } else {
#pragma unroll
          for (int r = 0; r < 4; ++r) {
            uint_t p = (uint_t)__shfl_xor((int)v[r], j);
            const bool up = ((((r << 6) | lane) & k) == 0);
            const bool lower = ((lane & j) == 0);
            v[r] = (up == lower) ? min(v[r], p) : max(v[r], p);
          }
        }
      }
    }
    float val[2];
#pragma unroll
    for (int r = 0; r < 2; ++r) {
      uint_t pk = v[r];
      uint_t idx = pk & 0xFFFFu;
      uint_t key = 0xFFFFu - (pk >> 16);
      uint_t ub = (key & 0x8000u) ? (key & 0x7FFFu) : (~key & 0xFFFFu);
      val[r] = fmaxf(__uint_as_float(ub << 16), 0.f);
      lidx[r * 64 + lane] = (int)idx;
      lval[r * 64 + lane] = val[r] * 0.0625f;   // pre-scaled for fp8 decode
    }
    float s1 = (lane < 32) ? val[0] : 0.f;
    float s2 = val[0] + val[1];
    for (int o = 32; o > 0; o >>= 1) { s1 += __shfl_down(s1, o); s2 += __shfl_down(s2, o); }
    if (lane == 0) { pS1[row] = (double)s1; pS2[row] = (double)s2; }
  }
  __syncthreads();

  // decode phase: packed-f32 FMA (v_pk_fma_f32), pre-scaled lval
  float l1 = 0.f, l2 = 0.f, dsum = 0.f;
  if (tid < 192) {
    const uint_t* Wt = Wd8 + tid;
    f32x2 a01 = {0.f, 0.f}, a23 = {0.f, 0.f};
#pragma unroll 1
    for (int g = 0; g < 16; ++g) {
      uint_t wb[8];
      float vv[8];
#pragma unroll
      for (int b = 0; b < 8; ++b) {
        wb[b] = Wt[(size_t)lidx[g * 8 + b] * 192];
        vv[b] = lval[g * 8 + b];
      }
#pragma unroll
      for (int b = 0; b < 8; ++b) {
        f32x2 vs2 = {vv[b], vv[b]};
        f32x2 lo = __builtin_amdgcn_cvt_pk_f32_fp8(wb[b], false);
        f32x2 hi = __builtin_amdgcn_cvt_pk_f32_fp8(wb[b], true);
        a01 += lo * vs2;
        a23 += hi * vs2;
      }
      if (g == 3) {
        float d0 = a01[0] + s4.x, d1 = a01[1] + s4.y, d2 = a23[0] + s4.z, d3 = a23[1] + s4.w;
        float e0 = m4.x - d0, e1 = m4.y - d1, e2 = m4.z - d2, e3 = m4.w - d3;
        l1 = e0 * e0 + e1 * e1 + e2 * e2 + e3 * e3;
        dsum = d0 + d1 + d2 + d3;
      }
    }
    float d0 = a01[0] + s4.x, d1 = a01[1] + s4.y, d2 = a23[0] + s4.z, d3 = a23[1] + s4.w;
    float e0 = m4.x - d0, e1 = m4.y - d1, e2 = m4.z - d2, e3 = m4.w - d3;
    l2 = e0 * e0 + e1 * e1 + e2 * e2 + e3 * e3;
    dsum += d0 + d1 + d2 + d3;
  }

  double r0 = (double)l1, r1 = (double)l2, r2 = (double)dsum;
  for (int o = 32; o > 0; o >>= 1) {
    r0 += __shfl_down(r0, o);
    r1 += __shfl_down(r1, o);
    r2 += __shfl_down(r2, o);
  }
  if ((tid & 63) == 0) { wred[wid][0] = r0; wred[wid][1] = r1; wred[wid][2] = r2; }
  __syncthreads();
  if (tid == 0) {
    pL1[row] = wred[0][0] + wred[1][0] + wred[2][0] + wred[3][0];
    pL2[row] = wred[0][1] + wred[1][1] + wred[2][1] + wred[3][1];
    pDS[row] = wred[0][2] + wred[1][2] + wred[2][2] + wred[3][2];
  }
}

// ---------------- finalize: reduce per-block partials ----------------
__global__ __launch_bounds__(256) void finalize_kernel(const double* __restrict__ accs,
                                                       const float* __restrict__ colsum,
                                                       const double* __restrict__ pL1,
                                                       const double* __restrict__ pL2,
                                                       const double* __restrict__ pDS,
                                                       const double* __restrict__ pS1,
                                                       const double* __restrict__ pS2,
                                                       float* __restrict__ out) {
  __shared__ double wred[4][6];
  const int tid = threadIdx.x;
  const int lane = tid & 63, wid = tid >> 6;
  double aL1 = 0, aL2 = 0, aDS = 0, aS1 = 0, aS2 = 0;
  for (int i = tid; i < 8192; i += 256) {
    aL1 += pL1[i]; aL2 += pL2[i]; aDS += pDS[i]; aS1 += pS1[i]; aS2 += pS2[i];
  }
  double c2 = 0.0;
  for (int i = tid; i < 768; i += 256) { double c = (double)colsum[i]; c2 += c * c; }
  for (int o = 32; o > 0; o >>= 1) {
    aL1 += __shfl_down(aL1, o);
    aL2 += __shfl_down(aL2, o);
    aDS += __shfl_down(aDS, o);
    aS1 += __shfl_down(aS1, o);
    aS2 += __shfl_down(aS2, o);
    c2  += __shfl_down(c2, o);
  }
  if (lane == 0) {
    wred[wid][0] = aL1; wred[wid][1] = aL2; wred[wid][2] = aDS;
    wred[wid][3] = aS1; wred[wid][4] = aS2; wred[wid][5] = c2;
  }
  __syncthreads();
  if (tid == 0) {
    double tL1 = 0, tL2 = 0, tDS = 0, tS1 = 0, tS2 = 0, csq = 0;
    for (int i = 0; i < 4; ++i) {
      tL1 += wred[i][0]; tL2 += wred[i][1]; tDS += wred[i][2];
      tS1 += wred[i][3]; tS2 += wred[i][4]; csq += wred[i][5];
    }
    double tv = accs[5] - csq / 8192.0;
    out[0] = (float)((tS1 + tS2) / (8192.0 * 12288.0));
    out[1] = (float)(tDS / (8192.0 * 768.0));
    out[2] = (float)(tL1 / tv + tL2 / (8.0 * tv));
  }
}

extern "C" void kernel_launch(void* const* d_in, const int* in_sizes, int n_in,
                              void* d_out, int out_size, void* d_ws, size_t ws_size,
                              hipStream_t stream) {
  const float* x    = (const float*)d_in[0];
  const float* mlp  = (const float*)d_in[1];
  const float* Wenc = (const float*)d_in[2];
  const float* benc = (const float*)d_in[3];
  const float* Wdec = (const float*)d_in[4];
  const float* bdec = (const float*)d_in[5];
  const float* Wskip= (const float*)d_in[6];

  char* ws = (char*)d_ws;
  const size_t OFF_COL  = 1024;
  const size_t OFF_XBF  = 8192;
  const size_t OFF_WENC = OFF_XBF  + (size_t)8192 * 768 * 2;
  const size_t OFF_WSK  = OFF_WENC + (size_t)12288 * 768 * 2;
  const size_t OFF_SKIP = OFF_WSK  + (size_t)768 * 768 * 2;
  const size_t OFF_PRE  = OFF_SKIP + (size_t)8192 * 768 * 4;

  double*   accs   = (double*)ws;
  float*    colsum = (float*)(ws + OFF_COL);
  ushort_t* xbf    = (ushort_t*)(ws + OFF_XBF);
  ushort_t* wencbf = (ushort_t*)(ws + OFF_WENC);
  ushort_t* wskT   = (ushort_t*)(ws + OFF_WSK);
  float*    skip   = (float*)(ws + OFF_SKIP);
  ushort_t* pre    = (ushort_t*)(ws + OFF_PRE);

  double* pL1 = (double*)(ws + OFF_XBF);   // xbf region dead after GEMMs
  double* pL2 = pL1 + 8192;
  double* pDS = pL1 + 16384;
  double* pS1 = pL1 + 24576;
  double* pS2 = pL1 + 32768;

  (void)hipMemsetAsync(d_ws, 0, 8192, stream);

  prep_x<<<256, 256, 0, stream>>>(x, xbf, colsum, accs);
  conv_bf16<<<(12288 * 768 / 4) / 256, 256, 0, stream>>>(Wenc, wencbf, 12288 * 768);
  conv_skipT<<<144, 256, 0, stream>>>(Wskip, wskT);

  gemm256<<<1536, 512, 0, stream>>>(xbf, wencbf, pre, benc, 768, 12288);
  gemm_bt<<<dim3(6, 64), 256, 0, stream>>>(xbf, wskT, skip, bdec, 768, 768);

  uint_t* wdec8 = (uint_t*)wencbf;   // reuse W_enc staging (dead after gemm256)
  conv_fp8<<<(12288 * 768 / 4 + 255) / 256, 256, 0, stream>>>(Wdec, wdec8, 12288 * 768 / 4);

  topk_decode<<<8192, 256, 0, stream>>>(pre, skip, mlp, wdec8, pS1, pS2, pL1, pL2, pDS);
  finalize_kernel<<<1, 256, 0, stream>>>(accs, colsum, pL1, pL2, pDS, pS1, pS2, (float*)d_out);
}

// Round 17
// 381.890 us; speedup vs baseline: 1.0232x; 1.0232x over previous
//
#include <hip/hip_runtime.h>

typedef unsigned short ushort_t;
typedef unsigned int uint_t;

typedef __attribute__((ext_vector_type(8))) short bf16x8;
typedef __attribute__((ext_vector_type(4))) float f32x4;
typedef __attribute__((ext_vector_type(2))) float f32x2;

#define GLOAD16(g, l) __builtin_amdgcn_global_load_lds( \
    (const __attribute__((address_space(1))) unsigned int*)(g), \
    (__attribute__((address_space(3))) unsigned int*)(l), 16, 0, 0)

#define VMCNT4 asm volatile("s_waitcnt vmcnt(4)" ::: "memory")
#define VMCNT2 asm volatile("s_waitcnt vmcnt(2)" ::: "memory")
#define VMCNT0 asm volatile("s_waitcnt vmcnt(0)" ::: "memory")
#define LGKM0  asm volatile("s_waitcnt lgkmcnt(0)" ::: "memory")
#define BARX   __builtin_amdgcn_s_barrier()

__device__ __forceinline__ ushort_t f2bf(float f) {
  union { float f; uint_t u; } c; c.f = f;
  uint_t u = c.u;
  return (ushort_t)((u + 0x7FFFu + ((u >> 16) & 1u)) >> 16);
}

// ---------------- prep: x -> bf16, colsum, sumsq ----------------
__global__ __launch_bounds__(256) void prep_x(const float* __restrict__ x,
                                              ushort_t* __restrict__ xbf,
                                              float* __restrict__ colsum,
                                              double* __restrict__ accs) {
  const int tid = threadIdx.x;
  const int r0 = blockIdx.x * 32;
  float cs0 = 0.f, cs1 = 0.f, cs2 = 0.f;
  double ss = 0.0;
  for (int r = 0; r < 32; ++r) {
    const float* xr = x + (size_t)(r0 + r) * 768;
    ushort_t* xo = xbf + (size_t)(r0 + r) * 768;
    float v0 = xr[tid], v1 = xr[tid + 256], v2 = xr[tid + 512];
    xo[tid] = f2bf(v0); xo[tid + 256] = f2bf(v1); xo[tid + 512] = f2bf(v2);
    cs0 += v0; cs1 += v1; cs2 += v2;
    ss += (double)v0 * v0 + (double)v1 * v1 + (double)v2 * v2;
  }
  atomicAdd(&colsum[tid], cs0);
  atomicAdd(&colsum[tid + 256], cs1);
  atomicAdd(&colsum[tid + 512], cs2);
  for (int o = 32; o > 0; o >>= 1) ss += __shfl_down(ss, o);
  __shared__ double wsum[4];
  if ((tid & 63) == 0) wsum[tid >> 6] = ss;
  __syncthreads();
  if (tid == 0) atomicAdd(&accs[5], wsum[0] + wsum[1] + wsum[2] + wsum[3]);
}

// ---------------- generic f32 -> bf16 convert ----------------
__global__ __launch_bounds__(256) void conv_bf16(const float* __restrict__ in,
                                                 ushort_t* __restrict__ out, int n) {
  int i = (blockIdx.x * 256 + threadIdx.x) * 4;
  if (i + 3 < n) {
    float4 v = *(const float4*)(in + i);
    uint_t a = (uint_t)f2bf(v.x) | ((uint_t)f2bf(v.y) << 16);
    uint_t b = (uint_t)f2bf(v.z) | ((uint_t)f2bf(v.w) << 16);
    *(uint2*)(out + i) = make_uint2(a, b);
  }
}

// ---------------- W_dec f32 -> fp8 e4m3 (x16 scale), 4 cols per uint ----------------
__global__ __launch_bounds__(256) void conv_fp8(const float* __restrict__ in,
                                                uint_t* __restrict__ out, int n4) {
  int i = blockIdx.x * 256 + threadIdx.x;
  if (i < n4) {
    float4 v = ((const float4*)in)[i];
    int w = 0;
    w = __builtin_amdgcn_cvt_pk_fp8_f32(v.x * 16.f, v.y * 16.f, w, false);
    w = __builtin_amdgcn_cvt_pk_fp8_f32(v.z * 16.f, v.w * 16.f, w, true);
    out[i] = (uint_t)w;
  }
}

// ---------------- W_skip transpose -> bf16 [D][K], LDS-tiled ----------------
__global__ __launch_bounds__(256) void conv_skipT(const float* __restrict__ in,
                                                  ushort_t* __restrict__ out) {
  __shared__ ushort_t tile[64][65];
  const int bx = blockIdx.x % 12, by = blockIdx.x / 12;
  const int lx = threadIdx.x & 63, ly = threadIdx.x >> 6;
#pragma unroll
  for (int r = 0; r < 16; ++r) {
    const int k = by * 64 + ly * 16 + r;
    tile[ly * 16 + r][lx] = f2bf(in[(size_t)k * 768 + bx * 64 + lx]);
  }
  __syncthreads();
#pragma unroll
  for (int r = 0; r < 16; ++r) {
    const int d = bx * 64 + ly * 16 + r;
    out[(size_t)d * 768 + by * 64 + lx] = tile[lx][ly * 16 + r];
  }
}

// ---------------- small bf16 GEMM (skip path): m97 structure ----------------
__global__ __launch_bounds__(256) void gemm_bt(const ushort_t* __restrict__ Ag,
                                               const ushort_t* __restrict__ Bg,
                                               float* __restrict__ Cg,
                                               const float* __restrict__ bias,
                                               int K, int ldc) {
  __shared__ __align__(16) char smem[34816];
  const int tid = threadIdx.x;
  const int lane = tid & 63, wid = tid >> 6;
  const int wr = wid >> 1, wc = wid & 1;
  const int lo = lane & 15, hi = lane >> 4;
  const int arow0 = blockIdx.y * 128, brow0 = blockIdx.x * 128;
  const int rr0 = (lane >> 2);
  const int kb = (lane & 3) * 8;
  f32x4 acc[4][4] = {};
  const int NT = K >> 5;
  for (int c = 0; c < 2; ++c) {
    int rr = (wid * 2 + c) * 16 + rr0;
    GLOAD16(Ag + (size_t)(arow0 + rr) * K + kb, smem + (wid * 2 + c) * 1024);
    GLOAD16(Bg + (size_t)(brow0 + rr) * K + kb, smem + 16384 + (wid * 2 + c) * 1024);
  }
  __syncthreads();
  for (int kt = 0; kt < NT; ++kt) {
    const int cur = (kt & 1) * 8192;
    const int nxt = 8192 - cur;
    if (kt + 1 < NT) {
      const int k0 = (kt + 1) << 5;
      for (int c = 0; c < 2; ++c) {
        int rr = (wid * 2 + c) * 16 + rr0;
        GLOAD16(Ag + (size_t)(arow0 + rr) * K + k0 + kb, smem + nxt + (wid * 2 + c) * 1024);
        GLOAD16(Bg + (size_t)(brow0 + rr) * K + k0 + kb, smem + 16384 + nxt + (wid * 2 + c) * 1024);
      }
    }
    const char* As = smem + cur;
    const char* Bs = smem + 16384 + cur;
    bf16x8 af[4], bfr[4];
#pragma unroll
    for (int m = 0; m < 4; ++m)
      af[m] = *(const bf16x8*)(As + ((wr * 64 + m * 16 + lo) * 64 + hi * 16));
#pragma unroll
    for (int n = 0; n < 4; ++n)
      bfr[n] = *(const bf16x8*)(Bs + ((wc * 64 + n * 16 + lo) * 64 + hi * 16));
#pragma unroll
    for (int m = 0; m < 4; ++m)
#pragma unroll
      for (int n = 0; n < 4; ++n)
        acc[m][n] = __builtin_amdgcn_mfma_f32_16x16x32_bf16(af[m], bfr[n], acc[m][n], 0, 0, 0);
    __syncthreads();
  }
#pragma unroll
  for (int n = 0; n < 4; ++n) {
    const int col = wc * 64 + n * 16 + lo;
    const float bv = bias[brow0 + col];
#pragma unroll
    for (int m = 0; m < 4; ++m)
#pragma unroll
      for (int r = 0; r < 4; ++r) {
        const int row = wr * 64 + m * 16 + hi * 4 + r;
        Cg[(size_t)(arow0 + row) * (size_t)ldc + brow0 + col] = acc[m][n][r] + bv;
      }
  }
}

// ---------------- 256x256 phase-pipelined bf16 GEMM (round-10/15 proven variant) ----------------
#define STAGE(G, grow0, kcol, L, S0, SS) do { \
    const int r_ = tid >> 3; \
    const int row_ = (S0) + (r_ & 31) + ((r_ >> 5) * (SS)); \
    GLOAD16((G) + (size_t)((grow0) + row_) * K + (kcol) + ((((tid & 7) ^ (r_ & 7))) << 3), \
            (L) + row_ * 128 + ((tid & 7) << 4)); \
  } while (0)

#define RD_A(MH) do { \
    _Pragma("unroll") for (int m_ = 0; m_ < 4; ++m_) { \
      const int row_ = wr * 128 + (MH) * 64 + m_ * 16 + lo; \
      _Pragma("unroll") for (int ks_ = 0; ks_ < 2; ++ks_) \
        af[m_][ks_] = *(const bf16x8*)(As + row_ * 128 + (((ks_ * 4 + hi) ^ (lo & 7)) << 4)); \
    } } while (0)

#define RD_B(NH, DST) do { \
    _Pragma("unroll") for (int n_ = 0; n_ < 2; ++n_) { \
      const int row_ = wc * 64 + (NH) * 32 + n_ * 16 + lo; \
      _Pragma("unroll") for (int ks_ = 0; ks_ < 2; ++ks_) \
        DST[n_][ks_] = *(const bf16x8*)(Bs + row_ * 128 + (((ks_ * 4 + hi) ^ (lo & 7)) << 4)); \
    } } while (0)

#define MM(MB, NB, BF) do { \
    __builtin_amdgcn_s_setprio(1); \
    _Pragma("unroll") for (int m_ = 0; m_ < 4; ++m_) \
      _Pragma("unroll") for (int n_ = 0; n_ < 2; ++n_) { \
        acc[(MB) + m_][(NB) + n_] = __builtin_amdgcn_mfma_f32_16x16x32_bf16(af[m_][0], BF[n_][0], acc[(MB) + m_][(NB) + n_], 0, 0, 0); \
        acc[(MB) + m_][(NB) + n_] = __builtin_amdgcn_mfma_f32_16x16x32_bf16(af[m_][1], BF[n_][1], acc[(MB) + m_][(NB) + n_], 0, 0, 0); \
      } \
    __builtin_amdgcn_s_setprio(0); \
  } while (0)

__global__ __launch_bounds__(512) void gemm256(const ushort_t* __restrict__ Ag,
                                               const ushort_t* __restrict__ Bg,
                                               ushort_t* __restrict__ Cg,
                                               const float* __restrict__ bias,
                                               int K, int ldc) {
  __shared__ __align__(16) char smem[69632];
  char* As = smem;
  char* Bs = smem + 32768;
  const int tid = threadIdx.x;
  const int lane = tid & 63, wid = tid >> 6;
  const int wr = wid >> 2, wc = wid & 3;
  const int lo = lane & 15, hi = lane >> 4;

  // L2-aware 2D mapping: each XCD owns 8 rows x 24 cols, as three 8x8 super-tiles.
  const int xcd = blockIdx.x & 7;
  const int idx = blockIdx.x >> 3;
  const int rg = xcd >> 1;
  const int cg = xcd & 1;
  const int st = idx >> 6;
  const int wi = idx & 63;
  const int brow0 = (rg * 8 + (wi & 7)) * 256;
  const int bcol0 = (cg * 24 + st * 8 + (wi >> 3)) * 256;

  const int NT = K >> 6;
  f32x4 acc[8][4] = {};
  bf16x8 af[4][2], b0[2][2], b1[2][2];

  STAGE(Ag, brow0, 0, As, 0, 32);   STAGE(Ag, brow0, 0, As, 128, 32);
  STAGE(Bg, bcol0, 0, Bs, 0, 64);   STAGE(Bg, bcol0, 0, Bs, 128, 64);
  STAGE(Bg, bcol0, 0, Bs, 32, 64);  STAGE(Bg, bcol0, 0, Bs, 160, 64);

  for (int kt = 0; kt < NT - 1; ++kt) {
    const int k0 = kt << 6, k1 = (kt + 1) << 6;
    STAGE(Ag, brow0, k0, As, 64, 32);  STAGE(Ag, brow0, k0, As, 192, 32);
    VMCNT4; BARX;
    RD_A(0); RD_B(0, b0);
    MM(0, 0, b0);
    BARX;
    STAGE(Ag, brow0, k1, As, 0, 32);   STAGE(Ag, brow0, k1, As, 128, 32);
    VMCNT4; BARX;
    RD_B(1, b1);
    MM(0, 2, b1);
    BARX;
    STAGE(Bg, bcol0, k1, Bs, 0, 64);   STAGE(Bg, bcol0, k1, Bs, 128, 64);
    VMCNT4; BARX;
    RD_A(1);
    MM(4, 0, b0);
    BARX;
    STAGE(Bg, bcol0, k1, Bs, 32, 64);  STAGE(Bg, bcol0, k1, Bs, 160, 64);
    MM(4, 2, b1);
  }
  {
    const int k0 = (NT - 1) << 6;
    STAGE(Ag, brow0, k0, As, 64, 32);  STAGE(Ag, brow0, k0, As, 192, 32);
    VMCNT4; BARX;
    RD_A(0); RD_B(0, b0);
    MM(0, 0, b0);
    BARX;
    VMCNT2; BARX;
    RD_B(1, b1);
    MM(0, 2, b1);
    BARX;
    VMCNT0; BARX;
    RD_A(1);
    MM(4, 0, b0);
    MM(4, 2, b1);
  }
  BARX;

  ushort_t* rep = (ushort_t*)smem;
#pragma unroll
  for (int h = 0; h < 2; ++h) {
    if (wr == h) {
#pragma unroll
      for (int n = 0; n < 4; ++n) {
        const int cl = wc * 64 + n * 16 + lo;
        const float bv = bias[bcol0 + cl];
#pragma unroll
        for (int m = 0; m < 8; ++m)
#pragma unroll
          for (int r = 0; r < 4; ++r)
            rep[(m * 16 + hi * 4 + r) * 264 + cl] = f2bf(acc[m][n][r] + bv);
      }
    }
    LGKM0; BARX;
    {
      const int rl = tid >> 2;
      const int c0 = tid & 3;
      ushort_t* dst = Cg + (size_t)(brow0 + h * 128 + rl) * (size_t)ldc + bcol0;
#pragma unroll
      for (int p = 0; p < 8; ++p)
        *(uint4*)(dst + (c0 + p * 4) * 8) = *(const uint4*)(rep + rl * 264 + (c0 + p * 4) * 8);
    }
    LGKM0; BARX;
  }
}

// ---------------- fused top-k + sparse decode + loss (one row per block) ----------------
#define EIDX(c, h) ((uint_t)(((c) >> 2) * 2048 + tid * 8 + (((c) & 3) << 1) + (h)))
#define HW(b) (((b) >> 4) * 17 + ((b) & 15))
__global__ __launch_bounds__(256) void topk_decode(const ushort_t* __restrict__ pre,
                                                   const float* __restrict__ skip,
                                                   const float* __restrict__ mlp,
                                                   const uint_t* __restrict__ Wd8,
                                                   double* __restrict__ pS1,
                                                   double* __restrict__ pS2,
                                                   double* __restrict__ pL1,
                                                   double* __restrict__ pL2,
                                                   double* __restrict__ pDS) {
  __shared__ uint_t hist[4352];
  __shared__ uint_t cand[256];
  __shared__ uint_t wtot[4];
  __shared__ uint_t ctl[4];
  __shared__ int lidx[128];
  __shared__ float lval[128];   // stores val * 0.0625 (exact pow-2 scale)
  __shared__ double wred[4][3];
  const int tid = threadIdx.x;
  const int lane = tid & 63, wid = tid >> 6;
  const size_t row = blockIdx.x;
  const uint4* pr4 = (const uint4*)(pre + row * 12288);

  float4 s4 = make_float4(0.f, 0.f, 0.f, 0.f), m4 = s4;
  if (tid < 192) {
    s4 = ((const float4*)(skip + row * 768))[tid];
    m4 = ((const float4*)(mlp + row * 768))[tid];
  }

  for (int i = tid; i < 4352; i += 256) hist[i] = 0;
  if (tid < 4) ctl[tid] = 0;
  __syncthreads();

  // pass 1: load row, packed dual-half monotone key transform, histogram
  uint_t k2[24];
#pragma unroll
  for (int i = 0; i < 6; ++i) {
    uint4 q = pr4[i * 256 + tid];
    uint_t qq[4] = { q.x, q.y, q.z, q.w };
#pragma unroll
    for (int w = 0; w < 4; ++w) {
      uint_t u2 = qq[w];
      uint_t m = ((u2 >> 15) & 0x00010001u) * 0x7FFFu;
      uint_t kk = u2 ^ (m | 0x80008000u);
      k2[i * 4 + w] = kk;
      atomicAdd(&hist[HW((kk & 0xFFFFu) >> 4)], 1u);
      atomicAdd(&hist[HW(kk >> 20)], 1u);
    }
  }
  __syncthreads();

  uint_t cs = 0;
#pragma unroll
  for (int b = 0; b < 16; ++b) cs += hist[tid * 17 + b];
  uint_t s = cs;
#pragma unroll
  for (int off = 1; off < 64; off <<= 1) {
    uint_t v = (uint_t)__shfl_down((int)s, off);
    if (lane + off < 64) s += v;
  }
  if (lane == 0) wtot[wid] = s;
  __syncthreads();
  uint_t above = 0;
  for (int w = wid + 1; w < 4; ++w) above += wtot[w];
  const uint_t Sg = s + above;
  const uint_t Snx = Sg - cs;
  if (Sg >= 128u && Snx < 128u) {
    uint_t running = Snx;
    for (int b = 15; b >= 0; --b) {
      uint_t c = hist[tid * 17 + b];
      if (running + c >= 128u) { ctl[0] = (uint_t)(tid * 16 + b); break; }
      running += c;
    }
  }
  __syncthreads();
  const uint_t b128 = ctl[0];

#pragma unroll
  for (int c = 0; c < 24; ++c) {
    uint_t kk = k2[c];
    uint_t key0 = kk & 0xFFFFu, key1 = kk >> 16;
    if ((key0 >> 4) >= b128) {
      uint_t p = atomicAdd(&ctl[1], 1u);
      if (p < 256u) cand[p] = ((0xFFFFu - key0) << 16) | EIDX(c, 0);
    }
    if ((key1 >> 4) >= b128) {
      uint_t p = atomicAdd(&ctl[1], 1u);
      if (p < 256u) cand[p] = ((0xFFFFu - key1) << 16) | EIDX(c, 1);
    }
  }
  __syncthreads();

  if (wid == 0) {
    const int n = (int)min(ctl[1], 256u);
    uint_t v[4];
#pragma unroll
    for (int r = 0; r < 4; ++r)
      v[r] = (r * 64 + lane < n) ? cand[r * 64 + lane] : 0xFFFFFFFFu;
#pragma unroll
    for (int k = 2; k <= 256; k <<= 1) {
#pragma unroll
      for (int j = 128; j > 0; j >>= 1) {
        if (j >= k) continue;
        if (j >= 64) {
          const int js = j >> 6;
#pragma unroll
          for (int r = 0; r < 4; ++r) {
            if ((r & js) == 0) {
              const int r2 = r | js;
              const bool up = (((r << 6) & k) == 0);
              uint_t a = v[r], b = v[r2];
              uint_t mn = min(a, b), mx = max(a, b);
              v[r] = up ? mn : mx;
              v[r2] = up ? mx : mn;
            }
          }
        } else {
#pragma unroll
          for (int r = 0; r < 4; ++r) {
            uint_t p = (uint_t)__shfl_xor((int)v[r], j);
            const bool up = ((((r << 6) | lane) & k) == 0);
            const bool lower = ((lane & j) == 0);
            v[r] = (up == lower) ? min(v[r], p) : max(v[r], p);
          }
        }
      }
    }
    float val[2];
#pragma unroll
    for (int r = 0; r < 2; ++r) {
      uint_t pk = v[r];
      uint_t idx = pk & 0xFFFFu;
      uint_t key = 0xFFFFu - (pk >> 16);
      uint_t ub = (key & 0x8000u) ? (key & 0x7FFFu) : (~key & 0xFFFFu);
      val[r] = fmaxf(__uint_as_float(ub << 16), 0.f);
      lidx[r * 64 + lane] = (int)idx;
      lval[r * 64 + lane] = val[r] * 0.0625f;   // pre-scaled for fp8 decode
    }
    float s1 = (lane < 32) ? val[0] : 0.f;
    float s2 = val[0] + val[1];
    for (int o = 32; o > 0; o >>= 1) { s1 += __shfl_down(s1, o); s2 += __shfl_down(s2, o); }
    if (lane == 0) { pS1[row] = (double)s1; pS2[row] = (double)s2; }
  }
  __syncthreads();

  // decode phase: packed-f32 FMA (v_pk_fma_f32), pre-scaled lval
  float l1 = 0.f, l2 = 0.f, dsum = 0.f;
  if (tid < 192) {
    const uint_t* Wt = Wd8 + tid;
    f32x2 a01 = {0.f, 0.f}, a23 = {0.f, 0.f};
#pragma unroll 1
    for (int g = 0; g < 16; ++g) {
      uint_t wb[8];
      float vv[8];
#pragma unroll
      for (int b = 0; b < 8; ++b) {
        wb[b] = Wt[(size_t)lidx[g * 8 + b] * 192];
        vv[b] = lval[g * 8 + b];
      }
#pragma unroll
      for (int b = 0; b < 8; ++b) {
        f32x2 vs2 = {vv[b], vv[b]};
        f32x2 lo = __builtin_amdgcn_cvt_pk_f32_fp8(wb[b], false);
        f32x2 hi = __builtin_amdgcn_cvt_pk_f32_fp8(wb[b], true);
        a01 += lo * vs2;
        a23 += hi * vs2;
      }
      if (g == 3) {
        float d0 = a01[0] + s4.x, d1 = a01[1] + s4.y, d2 = a23[0] + s4.z, d3 = a23[1] + s4.w;
        float e0 = m4.x - d0, e1 = m4.y - d1, e2 = m4.z - d2, e3 = m4.w - d3;
        l1 = e0 * e0 + e1 * e1 + e2 * e2 + e3 * e3;
        dsum = d0 + d1 + d2 + d3;
      }
    }
    float d0 = a01[0] + s4.x, d1 = a01[1] + s4.y, d2 = a23[0] + s4.z, d3 = a23[1] + s4.w;
    float e0 = m4.x - d0, e1 = m4.y - d1, e2 = m4.z - d2, e3 = m4.w - d3;
    l2 = e0 * e0 + e1 * e1 + e2 * e2 + e3 * e3;
    dsum += d0 + d1 + d2 + d3;
  }

  double r0 = (double)l1, r1 = (double)l2, r2 = (double)dsum;
  for (int o = 32; o > 0; o >>= 1) {
    r0 += __shfl_down(r0, o);
    r1 += __shfl_down(r1, o);
    r2 += __shfl_down(r2, o);
  }
  if ((tid & 63) == 0) { wred[wid][0] = r0; wred[wid][1] = r1; wred[wid][2] = r2; }
  __syncthreads();
  if (tid == 0) {
    pL1[row] = wred[0][0] + wred[1][0] + wred[2][0] + wred[3][0];
    pL2[row] = wred[0][1] + wred[1][1] + wred[2][1] + wred[3][1];
    pDS[row] = wred[0][2] + wred[1][2] + wred[2][2] + wred[3][2];
  }
}

// ---------------- finalize: reduce per-block partials ----------------
__global__ __launch_bounds__(256) void finalize_kernel(const double* __restrict__ accs,
                                                       const float* __restrict__ colsum,
                                                       const double* __restrict__ pL1,
                                                       const double* __restrict__ pL2,
                                                       const double* __restrict__ pDS,
                                                       const double* __restrict__ pS1,
                                                       const double* __restrict__ pS2,
                                                       float* __restrict__ out) {
  __shared__ double wred[4][6];
  const int tid = threadIdx.x;
  const int lane = tid & 63, wid = tid >> 6;
  double aL1 = 0, aL2 = 0, aDS = 0, aS1 = 0, aS2 = 0;
  for (int i = tid; i < 8192; i += 256) {
    aL1 += pL1[i]; aL2 += pL2[i]; aDS += pDS[i]; aS1 += pS1[i]; aS2 += pS2[i];
  }
  double c2 = 0.0;
  for (int i = tid; i < 768; i += 256) { double c = (double)colsum[i]; c2 += c * c; }
  for (int o = 32; o > 0; o >>= 1) {
    aL1 += __shfl_down(aL1, o);
    aL2 += __shfl_down(aL2, o);
    aDS += __shfl_down(aDS, o);
    aS1 += __shfl_down(aS1, o);
    aS2 += __shfl_down(aS2, o);
    c2  += __shfl_down(c2, o);
  }
  if (lane == 0) {
    wred[wid][0] = aL1; wred[wid][1] = aL2; wred[wid][2] = aDS;
    wred[wid][3] = aS1; wred[wid][4] = aS2; wred[wid][5] = c2;
  }
  __syncthreads();
  if (tid == 0) {
    double tL1 = 0, tL2 = 0, tDS = 0, tS1 = 0, tS2 = 0, csq = 0;
    for (int i = 0; i < 4; ++i) {
      tL1 += wred[i][0]; tL2 += wred[i][1]; tDS += wred[i][2];
      tS1 += wred[i][3]; tS2 += wred[i][4]; csq += wred[i][5];
    }
    double tv = accs[5] - csq / 8192.0;
    out[0] = (float)((tS1 + tS2) / (8192.0 * 12288.0));
    out[1] = (float)(tDS / (8192.0 * 768.0));
    out[2] = (float)(tL1 / tv + tL2 / (8.0 * tv));
  }
}

extern "C" void kernel_launch(void* const* d_in, const int* in_sizes, int n_in,
                              void* d_out, int out_size, void* d_ws, size_t ws_size,
                              hipStream_t stream) {
  const float* x    = (const float*)d_in[0];
  const float* mlp  = (const float*)d_in[1];
  const float* Wenc = (const float*)d_in[2];
  const float* benc = (const float*)d_in[3];
  const float* Wdec = (const float*)d_in[4];
  const float* bdec = (const float*)d_in[5];
  const float* Wskip= (const float*)d_in[6];

  char* ws = (char*)d_ws;
  const size_t OFF_COL  = 1024;
  const size_t OFF_XBF  = 8192;
  const size_t OFF_WENC = OFF_XBF  + (size_t)8192 * 768 * 2;
  const size_t OFF_WSK  = OFF_WENC + (size_t)12288 * 768 * 2;
  const size_t OFF_SKIP = OFF_WSK  + (size_t)768 * 768 * 2;
  const size_t OFF_PRE  = OFF_SKIP + (size_t)8192 * 768 * 4;

  double*   accs   = (double*)ws;
  float*    colsum = (float*)(ws + OFF_COL);
  ushort_t* xbf    = (ushort_t*)(ws + OFF_XBF);
  ushort_t* wencbf = (ushort_t*)(ws + OFF_WENC);
  ushort_t* wskT   = (ushort_t*)(ws + OFF_WSK);
  float*    skip   = (float*)(ws + OFF_SKIP);
  ushort_t* pre    = (ushort_t*)(ws + OFF_PRE);

  double* pL1 = (double*)(ws + OFF_XBF);   // xbf region dead after GEMMs
  double* pL2 = pL1 + 8192;
  double* pDS = pL1 + 16384;
  double* pS1 = pL1 + 24576;
  double* pS2 = pL1 + 32768;

  (void)hipMemsetAsync(d_ws, 0, 8192, stream);

  prep_x<<<256, 256, 0, stream>>>(x, xbf, colsum, accs);
  conv_bf16<<<(12288 * 768 / 4) / 256, 256, 0, stream>>>(Wenc, wencbf, 12288 * 768);
  conv_skipT<<<144, 256, 0, stream>>>(Wskip, wskT);

  gemm256<<<1536, 512, 0, stream>>>(xbf, wencbf, pre, benc, 768, 12288);
  gemm_bt<<<dim3(6, 64), 256, 0, stream>>>(xbf, wskT, skip, bdec, 768, 768);

  uint_t* wdec8 = (uint_t*)wencbf;   // reuse W_enc staging (dead after gemm256)
  conv_fp8<<<(12288 * 768 / 4 + 255) / 256, 256, 0, stream>>>(Wdec, wdec8, 12288 * 768 / 4);

  topk_decode<<<8192, 256, 0, stream>>>(pre, skip, mlp, wdec8, pS1, pS2, pL1, pL2, pDS);
  finalize_kernel<<<1, 256, 0, stream>>>(accs, colsum, pL1, pL2, pDS, pS1, pS2, (float*)d_out);
}